// Round 4
// baseline (3308.001 us; speedup 1.0000x reference)
//
#include <hip/hip_runtime.h>
#include <hip/hip_bf16.h>

// ============================================================================
// Qtran fused kernel, MI355X/gfx950.  Round 4: inputs are FP32 (per spec;
// round-3 NaN proved bf16-interp of inputs is wrong), and d_out is FP32
// (rounds 0-3 failures are fully explained by having written bf16 into an
// fp32-read output buffer: R0 zeros->3.14=max|ref| exactly-bf16 because the
// np REF is bf16-rounded; R1/R2 bf16-pairs-as-fp32 -> finite 2.99 garbage;
// R3 bf16-NaN patterns in upper halves -> NaN read-back).
// Phase A: fp32 VALU (enc, q_net, argmax) -- exact, feeds argmax.
// Phase B: bf16 MFMA 16x16x32 (vtot, lin2+onehot, q_prime, q_jt), wave 0 only.
// No d_ws usage.
// ============================================================================

#define B_TOT 262144

typedef __bf16 bf16_t;
typedef __bf16 bf16x8 __attribute__((ext_vector_type(8)));
typedef float  f32x4  __attribute__((ext_vector_type(4)));

#define MFMA16(a, b, c) __builtin_amdgcn_mfma_f32_16x16x32_bf16((a), (b), (c), 0, 0, 0)

// Orders LDS writes vs subsequent reads for the (single) wave in phase B.
#define LDS_SYNC() __builtin_amdgcn_fence(__ATOMIC_SEQ_CST, "workgroup")

// output element offsets (fp32 elements, concatenated tuple)
enum : int {
  O_Q1   = 0,
  O_Q2   = 21 * B_TOT,
  O_JQ   = 42 * B_TOT,
  O_JMQ  = 43 * B_TOT,
  O_VT   = 44 * B_TOT,
  O_QJT  = 45 * B_TOT,
  O_QJTM = 87 * B_TOT
};

struct Args {
  const float* x; const int* a1; const int* a2;
  const float* ew1; const float* eb1; const float* ew2; const float* eb2;
  const float* qw1; const float* qb1; const float* qw2; const float* qb2;
  const float* vw1; const float* vb1; const float* vw2; const float* vb2;
  const float* l2w1; const float* l2b1; const float* l2w2; const float* l2b2;
  const float* l2w3; const float* l2b3;
  const float* l3w;  const float* l3b;  const float* l4w;  const float* l4b;
  const float* qpw1; const float* qpb1; const float* qpw2; const float* qpb2;
  const float* qpw3; const float* qpb3; const float* qpw4; const float* qpb4;
  float* out;
};

struct __align__(16) SMem {
  bf16_t h1b[64 * 72];        // bf16 h1, A-frag friendly (stride 72)
  bf16_t h2b[64 * 72];
  unsigned char scr[35840];   // phase A: f0[64*68], f1[64*68] fp32
                              // phase B: st[64*136] bf16 staging, k1[64*144] bf16
  bf16_t oneh[21 * 64];       // l2_w1 rows 64..84 (one-hot add rows)
  float  bias[768];
  int    acts[128];           // b_act1[64] | b_act2[64]
  int    amax[128];           // argmax(q1)[64] | argmax(q2)[64]
  float  red[64][2];
  int    redi[64][2];
};

__device__ __forceinline__ float eluf(float x) { return x > 0.f ? x : expm1f(x); }

// fp32 64->64 layer: thread = (row r, colgroup g), relu, optional bf16 copy.
__device__ __forceinline__ void fcA64(const float* __restrict__ fin, float* __restrict__ fout,
                                      const float* __restrict__ W, const float* __restrict__ Bv,
                                      bf16_t* hb, int r, int g) {
  float2 acc[8];
#pragma unroll
  for (int i = 0; i < 8; i++) acc[i] = make_float2(Bv[g * 16 + 2 * i], Bv[g * 16 + 2 * i + 1]);
#pragma unroll 4
  for (int k4 = 0; k4 < 16; k4++) {
    float4 a = *(const float4*)(fin + r * 68 + k4 * 4);
    float av[4] = {a.x, a.y, a.z, a.w};
#pragma unroll
    for (int kk = 0; kk < 4; kk++) {
      const float2* wr = (const float2*)(W + (k4 * 4 + kk) * 64 + g * 16);  // wave-uniform
#pragma unroll
      for (int i = 0; i < 8; i++) {
        float2 w = wr[i];
        acc[i].x = fmaf(av[kk], w.x, acc[i].x);
        acc[i].y = fmaf(av[kk], w.y, acc[i].y);
      }
    }
  }
#pragma unroll
  for (int i = 0; i < 8; i++) {
    float v0 = fmaxf(acc[i].x, 0.f), v1 = fmaxf(acc[i].y, 0.f);
    fout[r * 68 + g * 16 + 2 * i]     = v0;
    fout[r * 68 + g * 16 + 2 * i + 1] = v1;
    if (hb) {
      hb[r * 72 + g * 16 + 2 * i]     = (bf16_t)v0;
      hb[r * 72 + g * 16 + 2 * i + 1] = (bf16_t)v1;
    }
  }
}

// fp32 64->NC final q layer + fp32 store + in-thread argmax (strict >, ascending)
template <int NC>
__device__ __forceinline__ void qn2(const float* __restrict__ fin, const float* __restrict__ W21,
                                    const float* __restrict__ Bv, float* __restrict__ qo,
                                    int r, int colbase, float& bv, int& bi) {
  float acc[NC];
#pragma unroll
  for (int i = 0; i < NC; i++) acc[i] = Bv[colbase + i];
  for (int k4 = 0; k4 < 16; k4++) {
    float4 a = *(const float4*)(fin + r * 68 + k4 * 4);
    float av[4] = {a.x, a.y, a.z, a.w};
#pragma unroll
    for (int kk = 0; kk < 4; kk++) {
      const float* wr = W21 + (k4 * 4 + kk) * 21 + colbase;  // wave-uniform
#pragma unroll
      for (int i = 0; i < NC; i++) acc[i] = fmaf(av[kk], wr[i], acc[i]);
    }
  }
  bv = -3e38f; bi = 0;
#pragma unroll
  for (int i = 0; i < NC; i++) {
    qo[i] = acc[i];
    if (acc[i] > bv) { bv = acc[i]; bi = colbase + i; }
  }
}

__global__ __launch_bounds__(256) void qtran_main(Args A) {
  __shared__ SMem sm;
  const int t = threadIdx.x;
  const int wgbase = blockIdx.x * 64;
  const int r = t & 63;
  const int g = __builtin_amdgcn_readfirstlane(t >> 6);

  float* f0 = (float*)sm.scr;
  float* f1 = f0 + 64 * 68;

  // ---- stage small tables (read only in/after phase B) ----
  // bias layout: 0 v_b1 | 64 l2_b1 | 128 l2_b2 | 192 l2_b3 | 256 qp_b1(128) | 384 qp_b2
  //            | 448 qp_b3 | 512 l3_b | 576 l4_b(pad32) | 608 v_w2 | 672 qp_w4 | 736 v_b2 | 737 qp_b4
  if (t < 64) {
    sm.bias[t]        = A.vb1[t];
    sm.bias[64 + t]   = A.l2b1[t];
    sm.bias[128 + t]  = A.l2b2[t];
    sm.bias[192 + t]  = A.l2b3[t];
    sm.bias[384 + t]  = A.qpb2[t];
    sm.bias[448 + t]  = A.qpb3[t];
    sm.bias[512 + t]  = A.l3b[t];
    sm.bias[608 + t]  = A.vw2[t];
    sm.bias[672 + t]  = A.qpw4[t];
    sm.acts[t]        = A.a1[wgbase + t];
    sm.acts[64 + t]   = A.a2[wgbase + t];
  } else if (t < 192) {
    sm.bias[256 + t - 64] = A.qpb1[t - 64];
  } else if (t < 224) {
    int i = t - 192;
    sm.bias[576 + i] = (i < 21) ? A.l4b[i] : 0.0f;
  } else if (t == 224) {
    sm.bias[736] = A.vb2[0];
    sm.bias[737] = A.qpb4[0];
  }
  for (int i = t; i < 21 * 64; i += 256)
    sm.oneh[i] = (bf16_t)A.l2w1[(64 + (i >> 6)) * 64 + (i & 63)];

  // =========================== phase A (fp32) ===========================
  const int rowg = wgbase + r;
  float4 xv = ((const float4*)A.x)[rowg];
#pragma unroll 1
  for (int s = 0; s < 2; ++s) {
    float xa = s ? xv.z : xv.x;
    float xb = s ? xv.w : xv.y;
#pragma unroll
    for (int cc = 0; cc < 16; cc++) {
      int col = g * 16 + cc;
      float h = fmaf(xa, A.ew1[col], fmaf(xb, A.ew1[64 + col], A.eb1[col]));
      f0[r * 68 + col] = fmaxf(h, 0.f);
    }
    __syncthreads();
    fcA64(f0, f1, A.ew2, A.eb2, s ? sm.h2b : sm.h1b, r, g);
    __syncthreads();
    fcA64(f1, f0, A.qw1, A.qb1, nullptr, r, g);
    __syncthreads();
    {
      float* qo = A.out + (s ? O_Q2 : O_Q1) + rowg * 21;
      float bv; int bi;
      if (g == 0) {
        qn2<16>(f0, A.qw2, A.qb2, qo, r, 0, bv, bi);
        sm.red[r][0] = bv; sm.redi[r][0] = bi;
      } else if (g == 1) {
        qn2<5>(f0, A.qw2, A.qb2, qo + 16, r, 16, bv, bi);
        sm.red[r][1] = bv; sm.redi[r][1] = bi;
      }
    }
    __syncthreads();
    if (t < 64)  // >= prefers lower column block => first-max semantics
      sm.amax[s * 64 + t] = (sm.red[t][0] >= sm.red[t][1]) ? sm.redi[t][0] : sm.redi[t][1];
    __syncthreads();
  }
  __syncthreads();

  // =========================== phase B (MFMA, wave 0 only) ===========================
  if (t >= 64) return;

  const int l = t, c = l & 15, q = l >> 4;
  bf16_t* st = (bf16_t*)sm.scr;           // [64][136] bf16 staging
  bf16_t* k1 = st + 64 * 136;             // [64][144] bf16: key1 j at col j*72
  float* out = A.out;

  // B-fragment gather straight from fp32 weights: lane l holds
  // B[k = kc*32 + q*8 + j][n = nt*16 + c], j = 0..7.
  auto BFG = [&](const float* __restrict__ W, int N, int kc, int nt) -> bf16x8 {
    int sk = kc * 32 + q * 8;
    int sn = nt * 16 + c;
    bf16x8 w;
    if (sn < N) {
#pragma unroll
      for (int j = 0; j < 8; j++) w[j] = (bf16_t)W[(sk + j) * N + sn];
    } else {
#pragma unroll
      for (int j = 0; j < 8; j++) w[j] = (bf16_t)0.0f;
    }
    return w;
  };
  auto AF = [&](const bf16_t* buf, int stride, int row, int ko) -> bf16x8 {
    return *(const bf16x8*)(buf + row * stride + ko);
  };

  // ---- vtot = relu((h1+h2)@v_w1 + v_b1) @ v_w2 + v_b2 ----
  {
    bf16x8 aS[4][2];
#pragma unroll
    for (int mt = 0; mt < 4; mt++)
#pragma unroll
      for (int kc = 0; kc < 2; kc++) {
        bf16x8 u = AF(sm.h1b, 72, mt * 16 + c, kc * 32 + q * 8);
        bf16x8 v = AF(sm.h2b, 72, mt * 16 + c, kc * 32 + q * 8);
        bf16x8 w;
#pragma unroll
        for (int i = 0; i < 8; i++) w[i] = (bf16_t)((float)u[i] + (float)v[i]);
        aS[mt][kc] = w;
      }
    float pr[4][4] = {};
#pragma unroll
    for (int nt = 0; nt < 4; nt++) {
      bf16x8 b0 = BFG(A.vw1, 64, 0, nt), b1 = BFG(A.vw1, 64, 1, nt);
      float bb = sm.bias[nt * 16 + c];
      float wv = sm.bias[608 + nt * 16 + c];
#pragma unroll
      for (int mt = 0; mt < 4; mt++) {
        f32x4 acc = {bb, bb, bb, bb};
        acc = MFMA16(aS[mt][0], b0, acc);
        acc = MFMA16(aS[mt][1], b1, acc);
#pragma unroll
        for (int rI = 0; rI < 4; rI++) pr[mt][rI] += fmaxf(acc[rI], 0.f) * wv;
      }
    }
#pragma unroll
    for (int mt = 0; mt < 4; mt++)
#pragma unroll
      for (int rI = 0; rI < 4; rI++) {
        float v = pr[mt][rI];
        v += __shfl_xor(v, 1, 64);
        v += __shfl_xor(v, 2, 64);
        v += __shfl_xor(v, 4, 64);
        v += __shfl_xor(v, 8, 64);
        if (c == 0)
          out[O_VT + wgbase + mt * 16 + q * 4 + rI] = v + sm.bias[736];
      }
  }

  // ---- joint(): lin2(concat(h_j, onehot)) -> key1; q_prime(mean); q_jt ----
  auto J = [&](const int* av1, const int* av2, int jointBase, int qjtBase) {
    LDS_SYNC();  // WAR vs previous uses of st/k1
#pragma unroll 1
    for (int j = 0; j < 2; j++) {
      const bf16_t* HB = j ? sm.h2b : sm.h1b;
      const int* av = j ? av2 : av1;
      int act[4][4];
#pragma unroll
      for (int mt = 0; mt < 4; mt++)
#pragma unroll
        for (int rI = 0; rI < 4; rI++) act[mt][rI] = av[mt * 16 + q * 4 + rI];
      bf16x8 aF[4][2];
#pragma unroll
      for (int mt = 0; mt < 4; mt++) {
        aF[mt][0] = AF(HB, 72, mt * 16 + c, q * 8);
        aF[mt][1] = AF(HB, 72, mt * 16 + c, 32 + q * 8);
      }
      // lin2 L1 (+ one-hot row add), relu
#pragma unroll
      for (int nt = 0; nt < 4; nt++) {
        bf16x8 b0 = BFG(A.l2w1, 64, 0, nt), b1 = BFG(A.l2w1, 64, 1, nt);
        float bb = sm.bias[64 + nt * 16 + c];
#pragma unroll
        for (int mt = 0; mt < 4; mt++) {
          f32x4 acc = {bb, bb, bb, bb};
          acc = MFMA16(aF[mt][0], b0, acc);
          acc = MFMA16(aF[mt][1], b1, acc);
#pragma unroll
          for (int rI = 0; rI < 4; rI++) {
            float v = acc[rI] + (float)sm.oneh[act[mt][rI] * 64 + nt * 16 + c];
            st[(mt * 16 + q * 4 + rI) * 136 + nt * 16 + c] = (bf16_t)fmaxf(v, 0.f);
          }
        }
      }
      LDS_SYNC();
      // lin2 L2, relu
#pragma unroll
      for (int mt = 0; mt < 4; mt++) {
        aF[mt][0] = AF(st, 136, mt * 16 + c, q * 8);
        aF[mt][1] = AF(st, 136, mt * 16 + c, 32 + q * 8);
      }
      LDS_SYNC();
#pragma unroll
      for (int nt = 0; nt < 4; nt++) {
        bf16x8 b0 = BFG(A.l2w2, 64, 0, nt), b1 = BFG(A.l2w2, 64, 1, nt);
        float bb = sm.bias[128 + nt * 16 + c];
#pragma unroll
        for (int mt = 0; mt < 4; mt++) {
          f32x4 acc = {bb, bb, bb, bb};
          acc = MFMA16(aF[mt][0], b0, acc);
          acc = MFMA16(aF[mt][1], b1, acc);
#pragma unroll
          for (int rI = 0; rI < 4; rI++)
            st[(mt * 16 + q * 4 + rI) * 136 + nt * 16 + c] = (bf16_t)fmaxf(acc[rI], 0.f);
        }
      }
      LDS_SYNC();
      // lin2 L3 (bare) -> key1_j
#pragma unroll
      for (int mt = 0; mt < 4; mt++) {
        aF[mt][0] = AF(st, 136, mt * 16 + c, q * 8);
        aF[mt][1] = AF(st, 136, mt * 16 + c, 32 + q * 8);
      }
      LDS_SYNC();
#pragma unroll
      for (int nt = 0; nt < 4; nt++) {
        bf16x8 b0 = BFG(A.l2w3, 64, 0, nt), b1 = BFG(A.l2w3, 64, 1, nt);
        float bb = sm.bias[192 + nt * 16 + c];
#pragma unroll
        for (int mt = 0; mt < 4; mt++) {
          f32x4 acc = {bb, bb, bb, bb};
          acc = MFMA16(aF[mt][0], b0, acc);
          acc = MFMA16(aF[mt][1], b1, acc);
#pragma unroll
          for (int rI = 0; rI < 4; rI++)
            k1[(mt * 16 + q * 4 + rI) * 144 + j * 72 + nt * 16 + c] = (bf16_t)acc[rI];
        }
      }
      LDS_SYNC();
    }
    // q_prime on mean(key1)
    bf16x8 aM[4][2];
#pragma unroll
    for (int mt = 0; mt < 4; mt++)
#pragma unroll
      for (int kc = 0; kc < 2; kc++) {
        bf16x8 u = AF(k1, 144, mt * 16 + c, kc * 32 + q * 8);
        bf16x8 v = AF(k1, 144, mt * 16 + c, 72 + kc * 32 + q * 8);
        bf16x8 m;
#pragma unroll
        for (int i = 0; i < 8; i++) m[i] = (bf16_t)(0.5f * ((float)u[i] + (float)v[i]));
        aM[mt][kc] = m;
      }
    // qp1: 64 -> 128, ELU
#pragma unroll
    for (int nt = 0; nt < 8; nt++) {
      bf16x8 b0 = BFG(A.qpw1, 128, 0, nt), b1 = BFG(A.qpw1, 128, 1, nt);
      float bb = sm.bias[256 + nt * 16 + c];
#pragma unroll
      for (int mt = 0; mt < 4; mt++) {
        f32x4 acc = {bb, bb, bb, bb};
        acc = MFMA16(aM[mt][0], b0, acc);
        acc = MFMA16(aM[mt][1], b1, acc);
#pragma unroll
        for (int rI = 0; rI < 4; rI++)
          st[(mt * 16 + q * 4 + rI) * 136 + nt * 16 + c] = (bf16_t)eluf(acc[rI]);
      }
    }
    LDS_SYNC();
    // qp2: 128 -> 64, ELU (reads staged 128 before overwriting low 64)
    {
      bf16x8 aQ[4][4];
#pragma unroll
      for (int mt = 0; mt < 4; mt++)
#pragma unroll
        for (int kc = 0; kc < 4; kc++) aQ[mt][kc] = AF(st, 136, mt * 16 + c, kc * 32 + q * 8);
      LDS_SYNC();
#pragma unroll
      for (int nt = 0; nt < 4; nt++) {
        bf16x8 bq0 = BFG(A.qpw2, 64, 0, nt), bq1 = BFG(A.qpw2, 64, 1, nt);
        bf16x8 bq2 = BFG(A.qpw2, 64, 2, nt), bq3 = BFG(A.qpw2, 64, 3, nt);
        float bb = sm.bias[384 + nt * 16 + c];
#pragma unroll
        for (int mt = 0; mt < 4; mt++) {
          f32x4 acc = {bb, bb, bb, bb};
          acc = MFMA16(aQ[mt][0], bq0, acc);
          acc = MFMA16(aQ[mt][1], bq1, acc);
          acc = MFMA16(aQ[mt][2], bq2, acc);
          acc = MFMA16(aQ[mt][3], bq3, acc);
#pragma unroll
          for (int rI = 0; rI < 4; rI++)
            st[(mt * 16 + q * 4 + rI) * 136 + nt * 16 + c] = (bf16_t)eluf(acc[rI]);
        }
      }
    }
    LDS_SYNC();
    // qp3 (ELU) fused with qp4 (64->1 dot) -> joint q
    {
      bf16x8 aP[4][2];
#pragma unroll
      for (int mt = 0; mt < 4; mt++) {
        aP[mt][0] = AF(st, 136, mt * 16 + c, q * 8);
        aP[mt][1] = AF(st, 136, mt * 16 + c, 32 + q * 8);
      }
      float pj[4][4] = {};
#pragma unroll
      for (int nt = 0; nt < 4; nt++) {
        bf16x8 b0 = BFG(A.qpw3, 64, 0, nt), b1 = BFG(A.qpw3, 64, 1, nt);
        float bb = sm.bias[448 + nt * 16 + c];
        float w4 = sm.bias[672 + nt * 16 + c];
#pragma unroll
        for (int mt = 0; mt < 4; mt++) {
          f32x4 acc = {bb, bb, bb, bb};
          acc = MFMA16(aP[mt][0], b0, acc);
          acc = MFMA16(aP[mt][1], b1, acc);
#pragma unroll
          for (int rI = 0; rI < 4; rI++) pj[mt][rI] += eluf(acc[rI]) * w4;
        }
      }
#pragma unroll
      for (int mt = 0; mt < 4; mt++)
#pragma unroll
        for (int rI = 0; rI < 4; rI++) {
          float v = pj[mt][rI];
          v += __shfl_xor(v, 1, 64);
          v += __shfl_xor(v, 2, 64);
          v += __shfl_xor(v, 4, 64);
          v += __shfl_xor(v, 8, 64);
          if (c == 0)
            out[jointBase + wgbase + mt * 16 + q * 4 + rI] = v + sm.bias[737];
        }
    }
    // q_jt: z_j = h_j + 0.5*key1_{other}; relu(z@l3)@l4
#pragma unroll 1
    for (int j = 0; j < 2; j++) {
      LDS_SYNC();  // WAR: st overwritten below vs prior reads
      const bf16_t* HB = j ? sm.h2b : sm.h1b;
      bf16x8 aZ[4][2];
#pragma unroll
      for (int mt = 0; mt < 4; mt++)
#pragma unroll
        for (int kc = 0; kc < 2; kc++) {
          bf16x8 u  = AF(HB, 72, mt * 16 + c, kc * 32 + q * 8);
          bf16x8 kk = AF(k1, 144, mt * 16 + c, (1 - j) * 72 + kc * 32 + q * 8);
          bf16x8 z;
#pragma unroll
          for (int i = 0; i < 8; i++) z[i] = (bf16_t)((float)u[i] + 0.5f * (float)kk[i]);
          aZ[mt][kc] = z;
        }
#pragma unroll
      for (int nt = 0; nt < 4; nt++) {
        bf16x8 b0 = BFG(A.l3w, 64, 0, nt), b1 = BFG(A.l3w, 64, 1, nt);
        float bb = sm.bias[512 + nt * 16 + c];
#pragma unroll
        for (int mt = 0; mt < 4; mt++) {
          f32x4 acc = {bb, bb, bb, bb};
          acc = MFMA16(aZ[mt][0], b0, acc);
          acc = MFMA16(aZ[mt][1], b1, acc);
#pragma unroll
          for (int rI = 0; rI < 4; rI++)
            st[(mt * 16 + q * 4 + rI) * 136 + nt * 16 + c] = (bf16_t)fmaxf(acc[rI], 0.f);
        }
      }
      LDS_SYNC();
      bf16x8 aL[4][2];
#pragma unroll
      for (int mt = 0; mt < 4; mt++) {
        aL[mt][0] = AF(st, 136, mt * 16 + c, q * 8);
        aL[mt][1] = AF(st, 136, mt * 16 + c, 32 + q * 8);
      }
#pragma unroll
      for (int nt = 0; nt < 2; nt++) {
        bf16x8 b0 = BFG(A.l4w, 21, 0, nt), b1 = BFG(A.l4w, 21, 1, nt);
        float bb = sm.bias[576 + nt * 16 + c];
        int col = nt * 16 + c;
#pragma unroll
        for (int mt = 0; mt < 4; mt++) {
          f32x4 acc = {bb, bb, bb, bb};
          acc = MFMA16(aL[mt][0], b0, acc);
          acc = MFMA16(aL[mt][1], b1, acc);
          if (col < 21) {
#pragma unroll
            for (int rI = 0; rI < 4; rI++)
              out[qjtBase + (wgbase + mt * 16 + q * 4 + rI) * 42 + j * 21 + col] = acc[rI];
          }
        }
      }
    }
  };

  J(sm.acts, sm.acts + 64, O_JQ, O_QJT);
  J(sm.amax, sm.amax + 64, O_JMQ, O_QJTM);
}

extern "C" void kernel_launch(void* const* d_in, const int* in_sizes, int n_in,
                              void* d_out, int out_size, void* d_ws, size_t ws_size,
                              hipStream_t stream) {
  (void)in_sizes; (void)n_in; (void)out_size; (void)d_ws; (void)ws_size;
  Args A;
  A.x    = (const float*)d_in[0];
  A.a1   = (const int*)d_in[1];
  A.a2   = (const int*)d_in[2];
  A.ew1  = (const float*)d_in[3];
  A.eb1  = (const float*)d_in[4];
  A.ew2  = (const float*)d_in[5];
  A.eb2  = (const float*)d_in[6];
  A.qw1  = (const float*)d_in[7];
  A.qb1  = (const float*)d_in[8];
  A.qw2  = (const float*)d_in[9];
  A.qb2  = (const float*)d_in[10];
  A.vw1  = (const float*)d_in[11];
  A.vb1  = (const float*)d_in[12];
  A.vw2  = (const float*)d_in[13];
  A.vb2  = (const float*)d_in[14];
  A.l2w1 = (const float*)d_in[15];
  A.l2b1 = (const float*)d_in[16];
  A.l2w2 = (const float*)d_in[17];
  A.l2b2 = (const float*)d_in[18];
  A.l2w3 = (const float*)d_in[19];
  A.l2b3 = (const float*)d_in[20];
  A.l3w  = (const float*)d_in[21];
  A.l3b  = (const float*)d_in[22];
  A.l4w  = (const float*)d_in[23];
  A.l4b  = (const float*)d_in[24];
  A.qpw1 = (const float*)d_in[25];
  A.qpb1 = (const float*)d_in[26];
  A.qpw2 = (const float*)d_in[27];
  A.qpb2 = (const float*)d_in[28];
  A.qpw3 = (const float*)d_in[29];
  A.qpb3 = (const float*)d_in[30];
  A.qpw4 = (const float*)d_in[31];
  A.qpb4 = (const float*)d_in[32];
  A.out  = (float*)d_out;
  hipLaunchKernelGGL(qtran_main, dim3(B_TOT / 64), dim3(256), 0, stream, A);
}

// Round 5
// 931.948 us; speedup vs baseline: 3.5496x; 3.5496x over previous
//
#include <hip/hip_runtime.h>
#include <hip/hip_bf16.h>

// ============================================================================
// Qtran fused kernel, MI355X/gfx950.  Round 5 (perf): R4 passed at 3308us with
// MfmaUtil 0.8 / VALUBusy 9.6 / Occ 5.4 -- latency-starved: 1-wave phase B +
// 8-scalar-load B-fragment gathers.  This round:
//   (1) phase B is wave-parallel: wave w owns rows [16w,16w+16) (all ops are
//       row-local; st/k1 LDS regions disjoint per wave).
//   (2) weights repacked once into d_ws as bf16 MFMA B-fragments -> each
//       fragment is ONE coalesced global_load_dwordx4 (falls back to gather
//       if ws_size too small; host-side uniform branch, graph-safe).
// Phase A: fp32 VALU (enc, q_net, argmax) -- exact, feeds argmax. Unchanged.
// ============================================================================

#define B_TOT 262144

typedef __bf16 bf16_t;
typedef __bf16 bf16x8 __attribute__((ext_vector_type(8)));
typedef float  f32x4  __attribute__((ext_vector_type(4)));

#define MFMA16(a, b, c) __builtin_amdgcn_mfma_f32_16x16x32_bf16((a), (b), (c), 0, 0, 0)
#define LDS_SYNC() __builtin_amdgcn_fence(__ATOMIC_SEQ_CST, "workgroup")

// fragment-packed weight offsets in ws (bf16 elements). Layout per matrix:
// (((kc*NT)+nt)*64 + lane)*8 + j  holds  W[kc*32 + (lane>>4)*8 + j][nt*16 + (lane&15)]
enum : int {
  OFF_VW1  = 0,
  OFF_L2W1 = 4096,
  OFF_L2W2 = 8192,
  OFF_L2W3 = 12288,
  OFF_L3W  = 16384,
  OFF_L4W  = 20480,
  OFF_QP1  = 22528,
  OFF_QP2  = 30720,
  OFF_QP3  = 38912,
  WS_ELEMS = 43008
};
#define WS_BYTES (WS_ELEMS * 2)

// output element offsets (fp32 elements, concatenated tuple)
enum : int {
  O_Q1   = 0,
  O_Q2   = 21 * B_TOT,
  O_JQ   = 42 * B_TOT,
  O_JMQ  = 43 * B_TOT,
  O_VT   = 44 * B_TOT,
  O_QJT  = 45 * B_TOT,
  O_QJTM = 87 * B_TOT
};

struct RDesc { const float* src; int K; int N; int NT; int off; };
struct RPack { RDesc d[9]; };

__global__ void repack_kernel(RPack P, bf16_t* __restrict__ ws) {
  RDesc d = P.d[blockIdx.x];
  int n = (d.K >> 5) * d.NT * 512;
  for (int i = threadIdx.x; i < n; i += blockDim.x) {
    int j  = i & 7;
    int l  = (i >> 3) & 63;
    int t  = i >> 9;          // kc*NT + nt
    int nt = t % d.NT;
    int kc = t / d.NT;
    int sk = kc * 32 + ((l >> 4) << 3) + j;
    int sn = nt * 16 + (l & 15);
    float v = (sn < d.N) ? d.src[sk * d.N + sn] : 0.0f;
    ws[d.off + i] = (bf16_t)v;
  }
}

struct Args {
  const float* x; const int* a1; const int* a2;
  const float* ew1; const float* eb1; const float* ew2; const float* eb2;
  const float* qw1; const float* qb1; const float* qw2; const float* qb2;
  const float* vw1; const float* vb1; const float* vw2; const float* vb2;
  const float* l2w1; const float* l2b1; const float* l2w2; const float* l2b2;
  const float* l2w3; const float* l2b3;
  const float* l3w;  const float* l3b;  const float* l4w;  const float* l4b;
  const float* qpw1; const float* qpb1; const float* qpw2; const float* qpb2;
  const float* qpw3; const float* qpb3; const float* qpw4; const float* qpb4;
  float* out; const bf16_t* ws;
};

struct __align__(16) SMem {
  bf16_t h1b[64 * 72];        // bf16 h1, A-frag friendly (stride 72)
  bf16_t h2b[64 * 72];
  unsigned char scr[35840];   // phase A: f0[64*68], f1[64*68] fp32
                              // phase B: st[64][136] bf16, k1[64][144] bf16
  bf16_t oneh[21 * 64];       // l2_w1 rows 64..84 (one-hot add rows)
  float  bias[768];
  int    acts[128];           // b_act1[64] | b_act2[64]
  int    amax[128];           // argmax(q1)[64] | argmax(q2)[64]
  float  red[64][2];
  int    redi[64][2];
};

__device__ __forceinline__ float eluf(float x) { return x > 0.f ? x : expm1f(x); }

// fp32 64->64 layer: thread = (row r, colgroup g), relu, optional bf16 copy.
__device__ __forceinline__ void fcA64(const float* __restrict__ fin, float* __restrict__ fout,
                                      const float* __restrict__ W, const float* __restrict__ Bv,
                                      bf16_t* hb, int r, int g) {
  float2 acc[8];
#pragma unroll
  for (int i = 0; i < 8; i++) acc[i] = make_float2(Bv[g * 16 + 2 * i], Bv[g * 16 + 2 * i + 1]);
#pragma unroll 4
  for (int k4 = 0; k4 < 16; k4++) {
    float4 a = *(const float4*)(fin + r * 68 + k4 * 4);
    float av[4] = {a.x, a.y, a.z, a.w};
#pragma unroll
    for (int kk = 0; kk < 4; kk++) {
      const float2* wr = (const float2*)(W + (k4 * 4 + kk) * 64 + g * 16);  // wave-uniform
#pragma unroll
      for (int i = 0; i < 8; i++) {
        float2 w = wr[i];
        acc[i].x = fmaf(av[kk], w.x, acc[i].x);
        acc[i].y = fmaf(av[kk], w.y, acc[i].y);
      }
    }
  }
#pragma unroll
  for (int i = 0; i < 8; i++) {
    float v0 = fmaxf(acc[i].x, 0.f), v1 = fmaxf(acc[i].y, 0.f);
    fout[r * 68 + g * 16 + 2 * i]     = v0;
    fout[r * 68 + g * 16 + 2 * i + 1] = v1;
    if (hb) {
      hb[r * 72 + g * 16 + 2 * i]     = (bf16_t)v0;
      hb[r * 72 + g * 16 + 2 * i + 1] = (bf16_t)v1;
    }
  }
}

// fp32 64->NC final q layer + fp32 store + in-thread argmax (strict >, ascending)
template <int NC>
__device__ __forceinline__ void qn2(const float* __restrict__ fin, const float* __restrict__ W21,
                                    const float* __restrict__ Bv, float* __restrict__ qo,
                                    int r, int colbase, float& bv, int& bi) {
  float acc[NC];
#pragma unroll
  for (int i = 0; i < NC; i++) acc[i] = Bv[colbase + i];
  for (int k4 = 0; k4 < 16; k4++) {
    float4 a = *(const float4*)(fin + r * 68 + k4 * 4);
    float av[4] = {a.x, a.y, a.z, a.w};
#pragma unroll
    for (int kk = 0; kk < 4; kk++) {
      const float* wr = W21 + (k4 * 4 + kk) * 21 + colbase;  // wave-uniform
#pragma unroll
      for (int i = 0; i < NC; i++) acc[i] = fmaf(av[kk], wr[i], acc[i]);
    }
  }
  bv = -3e38f; bi = 0;
#pragma unroll
  for (int i = 0; i < NC; i++) {
    qo[i] = acc[i];
    if (acc[i] > bv) { bv = acc[i]; bi = colbase + i; }
  }
}

template <bool USEWS>
__global__ __launch_bounds__(256) void qtran_main(Args A) {
  __shared__ SMem sm;
  const int t = threadIdx.x;
  const int wgbase = blockIdx.x * 64;
  const int r = t & 63;
  const int g = __builtin_amdgcn_readfirstlane(t >> 6);

  float* f0 = (float*)sm.scr;
  float* f1 = f0 + 64 * 68;

  // ---- stage small tables ----
  // bias layout: 0 v_b1 | 64 l2_b1 | 128 l2_b2 | 192 l2_b3 | 256 qp_b1(128) | 384 qp_b2
  //            | 448 qp_b3 | 512 l3_b | 576 l4_b(pad32) | 608 v_w2 | 672 qp_w4 | 736 v_b2 | 737 qp_b4
  if (t < 64) {
    sm.bias[t]        = A.vb1[t];
    sm.bias[64 + t]   = A.l2b1[t];
    sm.bias[128 + t]  = A.l2b2[t];
    sm.bias[192 + t]  = A.l2b3[t];
    sm.bias[384 + t]  = A.qpb2[t];
    sm.bias[448 + t]  = A.qpb3[t];
    sm.bias[512 + t]  = A.l3b[t];
    sm.bias[608 + t]  = A.vw2[t];
    sm.bias[672 + t]  = A.qpw4[t];
    sm.acts[t]        = A.a1[wgbase + t];
    sm.acts[64 + t]   = A.a2[wgbase + t];
  } else if (t < 192) {
    sm.bias[256 + t - 64] = A.qpb1[t - 64];
  } else if (t < 224) {
    int i = t - 192;
    sm.bias[576 + i] = (i < 21) ? A.l4b[i] : 0.0f;
  } else if (t == 224) {
    sm.bias[736] = A.vb2[0];
    sm.bias[737] = A.qpb4[0];
  }
  for (int i = t; i < 21 * 64; i += 256)
    sm.oneh[i] = (bf16_t)A.l2w1[(64 + (i >> 6)) * 64 + (i & 63)];

  // =========================== phase A (fp32) ===========================
  const int rowg = wgbase + r;
  float4 xv = ((const float4*)A.x)[rowg];
#pragma unroll 1
  for (int s = 0; s < 2; ++s) {
    float xa = s ? xv.z : xv.x;
    float xb = s ? xv.w : xv.y;
#pragma unroll
    for (int cc = 0; cc < 16; cc++) {
      int col = g * 16 + cc;
      float h = fmaf(xa, A.ew1[col], fmaf(xb, A.ew1[64 + col], A.eb1[col]));
      f0[r * 68 + col] = fmaxf(h, 0.f);
    }
    __syncthreads();
    fcA64(f0, f1, A.ew2, A.eb2, s ? sm.h2b : sm.h1b, r, g);
    __syncthreads();
    fcA64(f1, f0, A.qw1, A.qb1, nullptr, r, g);
    __syncthreads();
    {
      float* qo = A.out + (s ? O_Q2 : O_Q1) + rowg * 21;
      float bv; int bi;
      if (g == 0) {
        qn2<16>(f0, A.qw2, A.qb2, qo, r, 0, bv, bi);
        sm.red[r][0] = bv; sm.redi[r][0] = bi;
      } else if (g == 1) {
        qn2<5>(f0, A.qw2, A.qb2, qo + 16, r, 16, bv, bi);
        sm.red[r][1] = bv; sm.redi[r][1] = bi;
      }
    }
    __syncthreads();
    if (t < 64)  // >= prefers lower column block => first-max semantics
      sm.amax[s * 64 + t] = (sm.red[t][0] >= sm.red[t][1]) ? sm.redi[t][0] : sm.redi[t][1];
    __syncthreads();
  }
  __syncthreads();

  // ================== phase B (MFMA, all 4 waves; wave w owns 16 rows) ==================
  const int l = t & 63, c = l & 15, q = l >> 4;
  const int rb = g * 16;                  // this wave's row base (uniform)
  bf16_t* st = (bf16_t*)sm.scr;           // [64][136] bf16 staging (rows disjoint per wave)
  bf16_t* k1 = st + 64 * 136;             // [64][144] bf16: key1 j at col j*72
  float* out = A.out;
  const bf16x8* WF = (const bf16x8*)A.ws;

  // B-fragment: lane l holds B[k = kc*32 + q*8 + j][n = nt*16 + c], j=0..7.
  auto BF = [&](const float* __restrict__ Wp, int N, int woff, int kc, int nt, int NT) -> bf16x8 {
    if constexpr (USEWS) {
      (void)Wp; (void)N;
      return WF[(woff >> 3) + (kc * NT + nt) * 64 + l];
    } else {
      (void)woff;
      int sk = kc * 32 + q * 8, sn = nt * 16 + c;
      bf16x8 v;
      if (sn < N) {
#pragma unroll
        for (int j = 0; j < 8; j++) v[j] = (bf16_t)Wp[(sk + j) * N + sn];
      } else {
#pragma unroll
        for (int j = 0; j < 8; j++) v[j] = (bf16_t)0.0f;
      }
      return v;
    }
  };
  auto AF = [&](const bf16_t* buf, int stride, int row, int ko) -> bf16x8 {
    return *(const bf16x8*)(buf + row * stride + ko);
  };

  // ---- vtot = relu((h1+h2)@v_w1 + v_b1) @ v_w2 + v_b2 ----
  {
    bf16x8 aS[2];
#pragma unroll
    for (int kc = 0; kc < 2; kc++) {
      bf16x8 u = AF(sm.h1b, 72, rb + c, kc * 32 + q * 8);
      bf16x8 v = AF(sm.h2b, 72, rb + c, kc * 32 + q * 8);
      bf16x8 s8;
#pragma unroll
      for (int i = 0; i < 8; i++) s8[i] = (bf16_t)((float)u[i] + (float)v[i]);
      aS[kc] = s8;
    }
    float pr[4] = {};
#pragma unroll
    for (int nt = 0; nt < 4; nt++) {
      bf16x8 b0 = BF(A.vw1, 64, OFF_VW1, 0, nt, 4), b1 = BF(A.vw1, 64, OFF_VW1, 1, nt, 4);
      float bb = sm.bias[nt * 16 + c];
      float wv = sm.bias[608 + nt * 16 + c];
      f32x4 acc = {bb, bb, bb, bb};
      acc = MFMA16(aS[0], b0, acc);
      acc = MFMA16(aS[1], b1, acc);
#pragma unroll
      for (int rI = 0; rI < 4; rI++) pr[rI] += fmaxf(acc[rI], 0.f) * wv;
    }
#pragma unroll
    for (int rI = 0; rI < 4; rI++) {
      float v = pr[rI];
      v += __shfl_xor(v, 1, 64);
      v += __shfl_xor(v, 2, 64);
      v += __shfl_xor(v, 4, 64);
      v += __shfl_xor(v, 8, 64);
      if (c == 0)
        out[O_VT + wgbase + rb + q * 4 + rI] = v + sm.bias[736];
    }
  }

  // ---- joint(): lin2(concat(h_j, onehot)) -> key1; q_prime(mean); q_jt ----
  auto J = [&](const int* av1, const int* av2, int jointBase, int qjtBase) {
    LDS_SYNC();  // WAR vs previous uses of st/k1
#pragma unroll 1
    for (int j = 0; j < 2; j++) {
      const bf16_t* HB = j ? sm.h2b : sm.h1b;
      const int* av = j ? av2 : av1;
      int act[4];
#pragma unroll
      for (int rI = 0; rI < 4; rI++) act[rI] = av[rb + q * 4 + rI];
      bf16x8 aF0 = AF(HB, 72, rb + c, q * 8);
      bf16x8 aF1 = AF(HB, 72, rb + c, 32 + q * 8);
      // lin2 L1 (+ one-hot row add), relu
#pragma unroll
      for (int nt = 0; nt < 4; nt++) {
        bf16x8 b0 = BF(A.l2w1, 64, OFF_L2W1, 0, nt, 4), b1 = BF(A.l2w1, 64, OFF_L2W1, 1, nt, 4);
        float bb = sm.bias[64 + nt * 16 + c];
        f32x4 acc = {bb, bb, bb, bb};
        acc = MFMA16(aF0, b0, acc);
        acc = MFMA16(aF1, b1, acc);
#pragma unroll
        for (int rI = 0; rI < 4; rI++) {
          float v = acc[rI] + (float)sm.oneh[act[rI] * 64 + nt * 16 + c];
          st[(rb + q * 4 + rI) * 136 + nt * 16 + c] = (bf16_t)fmaxf(v, 0.f);
        }
      }
      LDS_SYNC();
      // lin2 L2, relu
      aF0 = AF(st, 136, rb + c, q * 8);
      aF1 = AF(st, 136, rb + c, 32 + q * 8);
      LDS_SYNC();
#pragma unroll
      for (int nt = 0; nt < 4; nt++) {
        bf16x8 b0 = BF(A.l2w2, 64, OFF_L2W2, 0, nt, 4), b1 = BF(A.l2w2, 64, OFF_L2W2, 1, nt, 4);
        float bb = sm.bias[128 + nt * 16 + c];
        f32x4 acc = {bb, bb, bb, bb};
        acc = MFMA16(aF0, b0, acc);
        acc = MFMA16(aF1, b1, acc);
#pragma unroll
        for (int rI = 0; rI < 4; rI++)
          st[(rb + q * 4 + rI) * 136 + nt * 16 + c] = (bf16_t)fmaxf(acc[rI], 0.f);
      }
      LDS_SYNC();
      // lin2 L3 (bare) -> key1_j
      aF0 = AF(st, 136, rb + c, q * 8);
      aF1 = AF(st, 136, rb + c, 32 + q * 8);
      LDS_SYNC();
#pragma unroll
      for (int nt = 0; nt < 4; nt++) {
        bf16x8 b0 = BF(A.l2w3, 64, OFF_L2W3, 0, nt, 4), b1 = BF(A.l2w3, 64, OFF_L2W3, 1, nt, 4);
        float bb = sm.bias[192 + nt * 16 + c];
        f32x4 acc = {bb, bb, bb, bb};
        acc = MFMA16(aF0, b0, acc);
        acc = MFMA16(aF1, b1, acc);
#pragma unroll
        for (int rI = 0; rI < 4; rI++)
          k1[(rb + q * 4 + rI) * 144 + j * 72 + nt * 16 + c] = (bf16_t)acc[rI];
      }
      LDS_SYNC();
    }
    // q_prime on mean(key1)
    bf16x8 aM[2];
#pragma unroll
    for (int kc = 0; kc < 2; kc++) {
      bf16x8 u = AF(k1, 144, rb + c, kc * 32 + q * 8);
      bf16x8 v = AF(k1, 144, rb + c, 72 + kc * 32 + q * 8);
      bf16x8 m;
#pragma unroll
      for (int i = 0; i < 8; i++) m[i] = (bf16_t)(0.5f * ((float)u[i] + (float)v[i]));
      aM[kc] = m;
    }
    // qp1: 64 -> 128, ELU
#pragma unroll
    for (int nt = 0; nt < 8; nt++) {
      bf16x8 b0 = BF(A.qpw1, 128, OFF_QP1, 0, nt, 8), b1 = BF(A.qpw1, 128, OFF_QP1, 1, nt, 8);
      float bb = sm.bias[256 + nt * 16 + c];
      f32x4 acc = {bb, bb, bb, bb};
      acc = MFMA16(aM[0], b0, acc);
      acc = MFMA16(aM[1], b1, acc);
#pragma unroll
      for (int rI = 0; rI < 4; rI++)
        st[(rb + q * 4 + rI) * 136 + nt * 16 + c] = (bf16_t)eluf(acc[rI]);
    }
    LDS_SYNC();
    // qp2: 128 -> 64, ELU (read full 128 into regs before overwriting low 64)
    {
      bf16x8 aQ[4];
#pragma unroll
      for (int kc = 0; kc < 4; kc++) aQ[kc] = AF(st, 136, rb + c, kc * 32 + q * 8);
      LDS_SYNC();
#pragma unroll
      for (int nt = 0; nt < 4; nt++) {
        bf16x8 bq0 = BF(A.qpw2, 64, OFF_QP2, 0, nt, 4), bq1 = BF(A.qpw2, 64, OFF_QP2, 1, nt, 4);
        bf16x8 bq2 = BF(A.qpw2, 64, OFF_QP2, 2, nt, 4), bq3 = BF(A.qpw2, 64, OFF_QP2, 3, nt, 4);
        float bb = sm.bias[384 + nt * 16 + c];
        f32x4 acc = {bb, bb, bb, bb};
        acc = MFMA16(aQ[0], bq0, acc);
        acc = MFMA16(aQ[1], bq1, acc);
        acc = MFMA16(aQ[2], bq2, acc);
        acc = MFMA16(aQ[3], bq3, acc);
#pragma unroll
        for (int rI = 0; rI < 4; rI++)
          st[(rb + q * 4 + rI) * 136 + nt * 16 + c] = (bf16_t)eluf(acc[rI]);
      }
    }
    LDS_SYNC();
    // qp3 (ELU) fused with qp4 (64->1 dot) -> joint q
    {
      bf16x8 aP0 = AF(st, 136, rb + c, q * 8);
      bf16x8 aP1 = AF(st, 136, rb + c, 32 + q * 8);
      float pj[4] = {};
#pragma unroll
      for (int nt = 0; nt < 4; nt++) {
        bf16x8 b0 = BF(A.qpw3, 64, OFF_QP3, 0, nt, 4), b1 = BF(A.qpw3, 64, OFF_QP3, 1, nt, 4);
        float bb = sm.bias[448 + nt * 16 + c];
        float w4 = sm.bias[672 + nt * 16 + c];
        f32x4 acc = {bb, bb, bb, bb};
        acc = MFMA16(aP0, b0, acc);
        acc = MFMA16(aP1, b1, acc);
#pragma unroll
        for (int rI = 0; rI < 4; rI++) pj[rI] += eluf(acc[rI]) * w4;
      }
#pragma unroll
      for (int rI = 0; rI < 4; rI++) {
        float v = pj[rI];
        v += __shfl_xor(v, 1, 64);
        v += __shfl_xor(v, 2, 64);
        v += __shfl_xor(v, 4, 64);
        v += __shfl_xor(v, 8, 64);
        if (c == 0)
          out[jointBase + wgbase + rb + q * 4 + rI] = v + sm.bias[737];
      }
    }
    // q_jt: z_j = h_j + 0.5*key1_{other}; relu(z@l3)@l4
#pragma unroll 1
    for (int j = 0; j < 2; j++) {
      LDS_SYNC();  // WAR: st overwritten below vs prior reads
      const bf16_t* HB = j ? sm.h2b : sm.h1b;
      bf16x8 aZ[2];
#pragma unroll
      for (int kc = 0; kc < 2; kc++) {
        bf16x8 u  = AF(HB, 72, rb + c, kc * 32 + q * 8);
        bf16x8 kk = AF(k1, 144, rb + c, (1 - j) * 72 + kc * 32 + q * 8);
        bf16x8 z;
#pragma unroll
        for (int i = 0; i < 8; i++) z[i] = (bf16_t)((float)u[i] + 0.5f * (float)kk[i]);
        aZ[kc] = z;
      }
#pragma unroll
      for (int nt = 0; nt < 4; nt++) {
        bf16x8 b0 = BF(A.l3w, 64, OFF_L3W, 0, nt, 4), b1 = BF(A.l3w, 64, OFF_L3W, 1, nt, 4);
        float bb = sm.bias[512 + nt * 16 + c];
        f32x4 acc = {bb, bb, bb, bb};
        acc = MFMA16(aZ[0], b0, acc);
        acc = MFMA16(aZ[1], b1, acc);
#pragma unroll
        for (int rI = 0; rI < 4; rI++)
          st[(rb + q * 4 + rI) * 136 + nt * 16 + c] = (bf16_t)fmaxf(acc[rI], 0.f);
      }
      LDS_SYNC();
      bf16x8 aL0 = AF(st, 136, rb + c, q * 8);
      bf16x8 aL1 = AF(st, 136, rb + c, 32 + q * 8);
#pragma unroll
      for (int nt = 0; nt < 2; nt++) {
        bf16x8 b0 = BF(A.l4w, 21, OFF_L4W, 0, nt, 2), b1 = BF(A.l4w, 21, OFF_L4W, 1, nt, 2);
        float bb = sm.bias[576 + nt * 16 + c];
        int col = nt * 16 + c;
        f32x4 acc = {bb, bb, bb, bb};
        acc = MFMA16(aL0, b0, acc);
        acc = MFMA16(aL1, b1, acc);
        if (col < 21) {
#pragma unroll
          for (int rI = 0; rI < 4; rI++)
            out[qjtBase + (wgbase + rb + q * 4 + rI) * 42 + j * 21 + col] = acc[rI];
        }
      }
    }
  };

  J(sm.acts, sm.acts + 64, O_JQ, O_QJT);
  J(sm.amax, sm.amax + 64, O_JMQ, O_QJTM);
}

extern "C" void kernel_launch(void* const* d_in, const int* in_sizes, int n_in,
                              void* d_out, int out_size, void* d_ws, size_t ws_size,
                              hipStream_t stream) {
  (void)in_sizes; (void)n_in; (void)out_size;
  Args A;
  A.x    = (const float*)d_in[0];
  A.a1   = (const int*)d_in[1];
  A.a2   = (const int*)d_in[2];
  A.ew1  = (const float*)d_in[3];
  A.eb1  = (const float*)d_in[4];
  A.ew2  = (const float*)d_in[5];
  A.eb2  = (const float*)d_in[6];
  A.qw1  = (const float*)d_in[7];
  A.qb1  = (const float*)d_in[8];
  A.qw2  = (const float*)d_in[9];
  A.qb2  = (const float*)d_in[10];
  A.vw1  = (const float*)d_in[11];
  A.vb1  = (const float*)d_in[12];
  A.vw2  = (const float*)d_in[13];
  A.vb2  = (const float*)d_in[14];
  A.l2w1 = (const float*)d_in[15];
  A.l2b1 = (const float*)d_in[16];
  A.l2w2 = (const float*)d_in[17];
  A.l2b2 = (const float*)d_in[18];
  A.l2w3 = (const float*)d_in[19];
  A.l2b3 = (const float*)d_in[20];
  A.l3w  = (const float*)d_in[21];
  A.l3b  = (const float*)d_in[22];
  A.l4w  = (const float*)d_in[23];
  A.l4b  = (const float*)d_in[24];
  A.qpw1 = (const float*)d_in[25];
  A.qpb1 = (const float*)d_in[26];
  A.qpw2 = (const float*)d_in[27];
  A.qpb2 = (const float*)d_in[28];
  A.qpw3 = (const float*)d_in[29];
  A.qpb3 = (const float*)d_in[30];
  A.qpw4 = (const float*)d_in[31];
  A.qpb4 = (const float*)d_in[32];
  A.out  = (float*)d_out;
  A.ws   = (const bf16_t*)d_ws;

  if (ws_size >= (size_t)WS_BYTES) {
    bf16_t* ws = (bf16_t*)d_ws;
    RPack P;
    P.d[0] = {A.vw1,  64, 64,  4, OFF_VW1};
    P.d[1] = {A.l2w1, 64, 64,  4, OFF_L2W1};   // rows 0..63 (one-hot rows via sm.oneh)
    P.d[2] = {A.l2w2, 64, 64,  4, OFF_L2W2};
    P.d[3] = {A.l2w3, 64, 64,  4, OFF_L2W3};
    P.d[4] = {A.l3w,  64, 64,  4, OFF_L3W};
    P.d[5] = {A.l4w,  64, 21,  2, OFF_L4W};    // N padded 21 -> 32 with zeros
    P.d[6] = {A.qpw1, 64, 128, 8, OFF_QP1};
    P.d[7] = {A.qpw2, 128, 64, 4, OFF_QP2};
    P.d[8] = {A.qpw3, 64, 64,  4, OFF_QP3};
    hipLaunchKernelGGL(repack_kernel, dim3(9), dim3(256), 0, stream, P, ws);
    hipLaunchKernelGGL(HIP_KERNEL_NAME(qtran_main<true>), dim3(B_TOT / 64), dim3(256), 0,
                       stream, A);
  } else {
    hipLaunchKernelGGL(HIP_KERNEL_NAME(qtran_main<false>), dim3(B_TOT / 64), dim3(256), 0,
                       stream, A);
  }
}